// Round 1
// baseline (88.905 us; speedup 1.0000x reference)
//
#include <hip/hip_runtime.h>

// Bit-exact integer reimplementation of the reference's fp64->fp32 circuit.
// d = IEEE-754 double bit pattern. Returns IEEE-754-style fp32 bit pattern
// following the reference circuit's exact semantics (incl. mux priority:
// nan > inf > underflow > overflow > rounded-normal).
__device__ __forceinline__ unsigned int fp64bits_to_fp32bits(unsigned long long d) {
    const unsigned int sign  = (unsigned int)(d >> 63);
    const unsigned int exp11 = (unsigned int)(d >> 52) & 0x7FFu;
    const unsigned long long mant52 = d & 0x000FFFFFFFFFFFFFull;

    const bool e_all = (exp11 == 0x7FFu);
    const bool m_any = (mant52 != 0ull);

    // 11-bit subtract (wraps), keep low 8 bits
    const unsigned int exp8   = (exp11 - 896u) & 0xFFu;
    // top 23 mantissa bits
    const unsigned int mant23 = (unsigned int)(mant52 >> 29);
    const unsigned int L = mant23 & 1u;                     // LSB of kept mantissa
    const unsigned int R = (unsigned int)(mant52 >> 28) & 1u; // round bit
    const unsigned int S = ((mant52 & 0x0FFFFFFFull) != 0ull) ? 1u : 0u; // sticky
    const unsigned int rup    = R & (S | L);
    const unsigned int mant24 = mant23 + rup;               // fits in 24 bits
    const unsigned int carry  = mant24 >> 23;
    const unsigned int mant   = mant24 & 0x7FFFFFu;
    const unsigned int fexp   = (exp8 + carry) & 0xFFu;

    unsigned int res = (sign << 31) | (fexp << 23) | mant;
    const unsigned int sgn31 = sign << 31;
    if (exp11 > 1150u)   res = sgn31 | 0x7F800000u;  // overflow -> inf
    if (exp11 < 897u)    res = sgn31;                // underflow -> signed zero
    if (e_all && !m_any) res = sgn31 | 0x7F800000u;  // inf
    if (e_all &&  m_any) res = sgn31 | 0x7FC00000u;  // nan (quiet-bit set)
    return res;
}

// One wave handles 8 elements per iteration:
//   - 8 coalesced dword loads (lane i reads bit i of the element)
//   - 8 ballots -> wave-uniform 64-bit masks; brev = fp64 bit pattern
//   - scalar (SALU) conversion per element
//   - one float4 store per lane: 8 elems * 32 bits = 256 floats = 64 lanes * 4
__global__ void __launch_bounds__(256) fp64_to_fp32_pulse_kernel(
        const float* __restrict__ in, float* __restrict__ out, int nElems)
{
    const int lane   = (int)(threadIdx.x & 63u);
    const int wave   = (int)((blockIdx.x * blockDim.x + threadIdx.x) >> 6);
    const int nWaves = (int)((gridDim.x * blockDim.x) >> 6);

    const int nGroups = nElems >> 3;   // groups of 8 elements

    for (int g = wave; g < nGroups; g += nWaves) {
        const long long ebase = (long long)g << 3;            // first element of group
        const float* __restrict__ p = in + (ebase << 6);      // 8*64 floats

        // 8 loads issued together for latency hiding
        const float v0 = p[0 * 64 + lane];
        const float v1 = p[1 * 64 + lane];
        const float v2 = p[2 * 64 + lane];
        const float v3 = p[3 * 64 + lane];
        const float v4 = p[4 * 64 + lane];
        const float v5 = p[5 * 64 + lane];
        const float v6 = p[6 * 64 + lane];
        const float v7 = p[7 * 64 + lane];

        const unsigned int r0 = fp64bits_to_fp32bits(__brevll(__ballot(v0 != 0.0f)));
        const unsigned int r1 = fp64bits_to_fp32bits(__brevll(__ballot(v1 != 0.0f)));
        const unsigned int r2 = fp64bits_to_fp32bits(__brevll(__ballot(v2 != 0.0f)));
        const unsigned int r3 = fp64bits_to_fp32bits(__brevll(__ballot(v3 != 0.0f)));
        const unsigned int r4 = fp64bits_to_fp32bits(__brevll(__ballot(v4 != 0.0f)));
        const unsigned int r5 = fp64bits_to_fp32bits(__brevll(__ballot(v5 != 0.0f)));
        const unsigned int r6 = fp64bits_to_fp32bits(__brevll(__ballot(v6 != 0.0f)));
        const unsigned int r7 = fp64bits_to_fp32bits(__brevll(__ballot(v7 != 0.0f)));

        // lane writes output floats [4*lane .. 4*lane+3] of the 256-float block;
        // its element index within the group is lane>>3. Explicit cndmask tree
        // (no runtime-indexed local array -> no scratch).
        const unsigned int s0 = (lane & 8)  ? r1 : r0;
        const unsigned int s1 = (lane & 8)  ? r3 : r2;
        const unsigned int s2 = (lane & 8)  ? r5 : r4;
        const unsigned int s3 = (lane & 8)  ? r7 : r6;
        const unsigned int t0 = (lane & 16) ? s1 : s0;
        const unsigned int t1 = (lane & 16) ? s3 : s2;
        const unsigned int r  = (lane & 32) ? t1 : t0;

        // output bit j (MSB-first): out[e*32 + j] = bit (31-j) of r.
        // this lane's j0 = 4*(lane&7); nibble = bits [31-j0 .. 28-j0]
        const int sh = 28 - ((lane & 7) << 2);
        const unsigned int nib = (r >> sh) & 0xFu;

        float4 o;
        o.x = (float)((nib >> 3) & 1u);
        o.y = (float)((nib >> 2) & 1u);
        o.z = (float)((nib >> 1) & 1u);
        o.w = (float)( nib       & 1u);

        *reinterpret_cast<float4*>(out + (ebase << 5) + (lane << 2)) = o;
    }

    // tail: whole elements one at a time (empty for B = 1048576)
    const int tailStart = nGroups << 3;
    for (int e = tailStart + wave; e < nElems; e += nWaves) {
        const float v = in[(long long)e * 64 + lane];
        const unsigned long long m = __ballot(v != 0.0f);
        const unsigned int r = fp64bits_to_fp32bits(__brevll(m));
        if (lane < 32) {
            out[(long long)e * 32 + lane] = (float)((r >> (31 - lane)) & 1u);
        }
    }
}

extern "C" void kernel_launch(void* const* d_in, const int* in_sizes, int n_in,
                              void* d_out, int out_size, void* d_ws, size_t ws_size,
                              hipStream_t stream) {
    (void)n_in; (void)d_ws; (void)ws_size; (void)out_size;
    const float* in = (const float*)d_in[0];
    float* out = (float*)d_out;

    const int nElems = in_sizes[0] / 64;   // 1048576 for this problem
    const int threads = 256;               // 4 waves/block
    const int nGroups = nElems >> 3;
    const int wavesPerBlock = threads / 64;
    int blocks = (nGroups + wavesPerBlock - 1) / wavesPerBlock;
    if (blocks > 2048) blocks = 2048;      // grid-stride the rest
    if (blocks < 1) blocks = 1;

    fp64_to_fp32_pulse_kernel<<<blocks, threads, 0, stream>>>(in, out, nElems);
}

// Round 2
// 79.733 us; speedup vs baseline: 1.1150x; 1.1150x over previous
//
#include <hip/hip_runtime.h>

// Bit-exact integer reimplementation of the reference's fp64->fp32 circuit.
// d = IEEE-754 double bit pattern. Returns IEEE-754-style fp32 bit pattern
// following the reference circuit's exact semantics (incl. mux priority:
// nan > inf > underflow > overflow > rounded-normal).
// NOTE: called with PER-LANE (VGPR) input so all of this runs on the VALU,
// not the single shared SALU (which was the R0 co-limiter at ~83% busy).
__device__ __forceinline__ unsigned int fp64bits_to_fp32bits(unsigned long long d) {
    const unsigned int sign  = (unsigned int)(d >> 63);
    const unsigned int exp11 = (unsigned int)(d >> 52) & 0x7FFu;
    const unsigned long long mant52 = d & 0x000FFFFFFFFFFFFFull;

    const bool e_all = (exp11 == 0x7FFu);
    const bool m_any = (mant52 != 0ull);

    // 11-bit subtract (wraps), keep low 8 bits
    const unsigned int exp8   = (exp11 - 896u) & 0xFFu;
    // top 23 mantissa bits
    const unsigned int mant23 = (unsigned int)(mant52 >> 29);
    const unsigned int L = mant23 & 1u;                       // LSB of kept mantissa
    const unsigned int R = (unsigned int)(mant52 >> 28) & 1u; // round bit
    const unsigned int S = ((mant52 & 0x0FFFFFFFull) != 0ull) ? 1u : 0u; // sticky
    const unsigned int rup    = R & (S | L);
    const unsigned int mant24 = mant23 + rup;                 // fits in 24 bits
    const unsigned int carry  = mant24 >> 23;
    const unsigned int mant   = mant24 & 0x7FFFFFu;
    const unsigned int fexp   = (exp8 + carry) & 0xFFu;

    unsigned int res = (sign << 31) | (fexp << 23) | mant;
    const unsigned int sgn31 = sign << 31;
    if (exp11 > 1150u)   res = sgn31 | 0x7F800000u;  // overflow -> inf
    if (exp11 < 897u)    res = sgn31;                // underflow -> signed zero
    if (e_all && !m_any) res = sgn31 | 0x7F800000u;  // inf
    if (e_all &&  m_any) res = sgn31 | 0x7FC00000u;  // nan (quiet-bit set)
    return res;
}

// One wave handles 16 elements per iteration:
//   - 16 coalesced dword loads (lane i reads bit i of each element); all 16
//     share one address register via offset: immediates (15*256B < 4096)
//   - 16 ballots -> wave-uniform 64-bit masks
//   - per-lane 64-bit cndmask tree picks the mask of element (lane>>3) in
//     each 8-element group; conversion then runs per-lane on the VALU
//   - two float4 stores per lane: 2 * (8 elems * 32 bits) = 2 * 256 floats
__global__ void __launch_bounds__(256) fp64_to_fp32_pulse_kernel(
        const float* __restrict__ in, float* __restrict__ out, int nElems)
{
    const int lane   = (int)(threadIdx.x & 63u);
    const int wave   = (int)((blockIdx.x * blockDim.x + threadIdx.x) >> 6);
    const int nWaves = (int)((gridDim.x * blockDim.x) >> 6);

    // hoisted per-lane select conditions + store nibble shift
    const bool selA = (lane & 8)  != 0;
    const bool selB = (lane & 16) != 0;
    const bool selC = (lane & 32) != 0;
    const int  sh   = 28 - ((lane & 7) << 2);

    const int nPairs = nElems >> 4;   // 16 elements per iteration

    for (int g = wave; g < nPairs; g += nWaves) {
        const long long ebase = (long long)g << 4;            // first element
        const float* __restrict__ p = in + (ebase << 6);      // 16*64 floats

        float v[16];
        #pragma unroll
        for (int k = 0; k < 16; ++k) v[k] = p[k * 64 + lane]; // 16 loads in flight

        unsigned long long m[16];
        #pragma unroll
        for (int k = 0; k < 16; ++k) m[k] = __ballot(v[k] != 0.0f);

        // per-lane 64-bit select tree: element (lane>>3) of each 8-group.
        // all indices compile-time constant -> registers, no scratch.
        const unsigned long long a0 = selA ? m[1]  : m[0];
        const unsigned long long a1 = selA ? m[3]  : m[2];
        const unsigned long long a2 = selA ? m[5]  : m[4];
        const unsigned long long a3 = selA ? m[7]  : m[6];
        const unsigned long long a4 = selA ? m[9]  : m[8];
        const unsigned long long a5 = selA ? m[11] : m[10];
        const unsigned long long a6 = selA ? m[13] : m[12];
        const unsigned long long a7 = selA ? m[15] : m[14];
        const unsigned long long b0 = selB ? a1 : a0;
        const unsigned long long b1 = selB ? a3 : a2;
        const unsigned long long b2 = selB ? a5 : a4;
        const unsigned long long b3 = selB ? a7 : a6;
        const unsigned long long e0 = selC ? b1 : b0;   // group 0 (elems 0..7)
        const unsigned long long e1 = selC ? b3 : b2;   // group 1 (elems 8..15)

        // per-lane VALU conversion (bit-reverse: lane0-MSB-first -> IEEE)
        const unsigned int r0 = fp64bits_to_fp32bits(__brevll(e0));
        const unsigned int r1 = fp64bits_to_fp32bits(__brevll(e1));

        // output bit j (MSB-first): out[e*32 + j] = bit (31-j) of r.
        const unsigned int nib0 = (r0 >> sh) & 0xFu;
        const unsigned int nib1 = (r1 >> sh) & 0xFu;

        float4 o0, o1;
        o0.x = (float)((nib0 >> 3) & 1u);
        o0.y = (float)((nib0 >> 2) & 1u);
        o0.z = (float)((nib0 >> 1) & 1u);
        o0.w = (float)( nib0       & 1u);
        o1.x = (float)((nib1 >> 3) & 1u);
        o1.y = (float)((nib1 >> 2) & 1u);
        o1.z = (float)((nib1 >> 1) & 1u);
        o1.w = (float)( nib1       & 1u);

        float* __restrict__ q = out + (ebase << 5) + (lane << 2);
        *reinterpret_cast<float4*>(q)       = o0;
        *reinterpret_cast<float4*>(q + 256) = o1;
    }

    // tail: whole elements one at a time (empty for B = 1048576)
    const int tailStart = nPairs << 4;
    for (int e = tailStart + wave; e < nElems; e += nWaves) {
        const float v = in[(long long)e * 64 + lane];
        const unsigned long long mm = __ballot(v != 0.0f);
        const unsigned int r = fp64bits_to_fp32bits(__brevll(mm));
        if (lane < 32) {
            out[(long long)e * 32 + lane] = (float)((r >> (31 - lane)) & 1u);
        }
    }
}

extern "C" void kernel_launch(void* const* d_in, const int* in_sizes, int n_in,
                              void* d_out, int out_size, void* d_ws, size_t ws_size,
                              hipStream_t stream) {
    (void)n_in; (void)d_ws; (void)ws_size; (void)out_size;
    const float* in = (const float*)d_in[0];
    float* out = (float*)d_out;

    const int nElems = in_sizes[0] / 64;   // 1048576 for this problem
    const int threads = 256;               // 4 waves/block
    const int nPairs = nElems >> 4;
    const int wavesPerBlock = threads / 64;
    int blocks = (nPairs + wavesPerBlock - 1) / wavesPerBlock;
    if (blocks > 2048) blocks = 2048;      // grid-stride the rest
    if (blocks < 1) blocks = 1;

    fp64_to_fp32_pulse_kernel<<<blocks, threads, 0, stream>>>(in, out, nElems);
}